// Round 20
// baseline (83.158 us; speedup 1.0000x reference)
//
#include <hip/hip_runtime.h>
#include <math.h>

#define NN 257
#define NN2 66049        // 257*257
#define PROW 260         // padded psf row stride (floats)
#define PCH (PROW * NN)
#define NRZ 17           // psf-row chunks of 8 (17*8=136 >= 135 rows per y-tile of 8)
#define FSW 288

#define SWG(f) (((((f) >> 2) ^ (((f) >> 5) & 7)) << 2))
#define SW(f) (SWG(f) | ((f) & 3))

static const double D_PI = 3.14159265358979323846;

__device__ __forceinline__ double lam_of(int c) {
    return c == 0 ? 610e-9 : (c == 1 ? 530e-9 : 470e-9);
}

__device__ __forceinline__ float2 phase_of(double rev) {
    rev -= floor(rev);
    float ang = (float)(2.0 * D_PI * rev);
    float sv, cv;
    __sincosf(ang, &sv, &cv);
    return make_float2(cv, sv);
}

// ---------------- DFT pass: 2 b-columns/block, 2 a-values/thread (R17 known-good) ----------------
// Math: out(b, a) = sum_t colval(t,b) * exp(SIGN*2*pi*i*a*t/257)
// STORAGE TRANSPOSED: element (b, a) at out[(c*NN + a)*NN + b] -> coalesced staging reads.
// MODE 0: aperture field generated (z1 = in-block depth mean); b in {0..127, 256};
//         mirror out(255-b, (257-a)%257) = w^{2a} * out(b, a)
// MODE 1: b in {0..128}; mirror out(257-b, (257-a)%257) = w^{2(a+b)} * out(b, a)
// MODE 2: H-mult, full b, a in {0..127, 256} only (grid.x = 1); zeroes sums[c]
// MODE 3: b in {0..127, 256}; |.|^2 into raw, mirrored via psf point symmetry
template <int SIGN, int MODE>
__global__ __launch_bounds__(256) void k_dft(const float2* __restrict__ in, float2* __restrict__ out,
                                             const float* __restrict__ depth,
                                             float* __restrict__ raw, double* __restrict__ sums) {
    __shared__ float4 col[NN];       // {re0, im0, re1, im1}
    __shared__ float2 twL[NN];
    __shared__ float4 sacc2[3][64][2];
    __shared__ float4 red[4];
    const int ah = blockIdx.x;       // a-half
    const int by = blockIdx.y;       // b-pair
    const int c = blockIdx.z;
    int bc0, bc1;
    if (MODE == 0 || MODE == 3) {
        bc0 = (by < 64) ? 2 * by : 256;
        bc1 = (by < 64) ? bc0 + 1 : 256;
    } else if (MODE == 1) {
        bc0 = (by < 64) ? 2 * by : 128;
        bc1 = (by < 64) ? bc0 + 1 : 128;
    } else {
        bc0 = 2 * by;
        bc1 = (bc0 < 256) ? bc0 + 1 : 256;
    }
    const float dupf = (bc1 == bc0) ? 0.f : 1.f;
    const int tid = threadIdx.x;

    if (MODE == 2) {  // zero channel sums ahead of pass 4 (stream-ordered)
        if (ah == 0 && by == 0 && tid == 0) sums[c] = 0.0;
    }

    // ---- twiddle table ----
    for (int t = tid; t < NN; t += 256) {
        double th = 2.0 * D_PI * (double)t / 257.0;
        double sv, cv; sincos(th, &sv, &cv);
        twL[t] = make_float2((float)cv, (float)(-sv));   // exp(-2*pi*i*t/257)
    }

    // ---- MODE 0: block-local depth mean (identical reduction order -> identical z1) ----
    double z1 = 0.0;
    if (MODE == 0) {
        double* sred = (double*)sacc2;
        double acc = 0.0;
        for (int i = tid; i < 16384; i += 256) acc += (double)depth[i];
        sred[tid] = acc;
        __syncthreads();
        for (int o = 128; o > 0; o >>= 1) {
            if (tid < o) sred[tid] += sred[tid + o];
            __syncthreads();
        }
        z1 = sred[0] / 16384.0;
        __syncthreads();
    }

    for (int t = tid; t < NN; t += 256) {
        float2 v0, v1;
        if (MODE == 0) {
            int js = t + 129; if (js >= NN) js -= NN;
            const double step = 0.01 / 256.0;
            double yy = -0.005 + js * step;
            double lam = lam_of(c);
            const double ap = 0.5 * (0.01 / 257.0) * 128.0 + 1e-7;
            {
                int is = bc0 + 129; if (is >= NN) is -= NN;
                double x = -0.005 + is * step;
                double r2 = x * x + yy * yy;
                v0 = make_float2(0.f, 0.f);
                if (sqrt(r2) <= ap) v0 = phase_of(sqrt(r2 + z1 * z1) / lam);
            }
            {
                int is = bc1 + 129; if (is >= NN) is -= NN;
                double x = -0.005 + is * step;
                double r2 = x * x + yy * yy;
                v1 = make_float2(0.f, 0.f);
                if (sqrt(r2) <= ap) v1 = phase_of(sqrt(r2 + z1 * z1) / lam);
            }
        } else {
            v0 = in[(c * NN + bc0) * NN + t];   // coalesced (transposed layout)
            v1 = in[(c * NN + bc1) * NN + t];
            if (MODE == 2) {
                int ps = t + 129; if (ps >= NN) ps -= NN;
                const double fstep = 25700.0 / 256.0;
                double fy = -12850.0 + ps * fstep;
                double lam = lam_of(c);
                double ilam2 = 1.0 / (lam * lam);
                double kzr = 0.05 / lam;
                {
                    int qs = bc0 + 129; if (qs >= NN) qs -= NN;
                    double fx = -12850.0 + qs * fstep;
                    double lfx = lam * fx, lfy = lam * fy;
                    double a2 = 1.0 - lfx * lfx - lfy * lfy;
                    float2 hh = make_float2(0.f, 0.f);
                    if (fx * fx + fy * fy < ilam2) hh = phase_of(kzr * sqrt(a2 > 0.0 ? a2 : 0.0));
                    v0 = make_float2(v0.x * hh.x - v0.y * hh.y, v0.x * hh.y + v0.y * hh.x);
                }
                {
                    int qs = bc1 + 129; if (qs >= NN) qs -= NN;
                    double fx = -12850.0 + qs * fstep;
                    double lfx = lam * fx, lfy = lam * fy;
                    double a2 = 1.0 - lfx * lfx - lfy * lfy;
                    float2 hh = make_float2(0.f, 0.f);
                    if (fx * fx + fy * fy < ilam2) hh = phase_of(kzr * sqrt(a2 > 0.0 ? a2 : 0.0));
                    v1 = make_float2(v1.x * hh.x - v1.y * hh.y, v1.x * hh.y + v1.y * hh.x);
                }
            }
        }
        col[t] = make_float4(v0.x, v0.y, v1.x, v1.y);
    }
    __syncthreads();

    const float invn4 = (float)(1.0 / ((double)NN2 * (double)NN2));
    const int q = tid >> 6;          // t-quarter (t ≡ q mod 4)
    const int al = tid & 63;
    int aval[2];
    aval[0] = ah * 128 + al;
    aval[1] = aval[0] + 64;

    // per-a: 4 twiddle chains (t = q+4m+16j), step omega^{16a}
    float cx[2][4], cy[2][4], wx[2], wy[2];
    #pragma unroll
    for (int aa = 0; aa < 2; ++aa) {
        #pragma unroll
        for (int m = 0; m < 4; ++m) {
            int sm = (aval[aa] * (q + 4 * m)) % 257;
            float2 tt = twL[sm];
            cx[aa][m] = tt.x; cy[aa][m] = -SIGN * tt.y;
        }
        float2 w16 = twL[(16 * aval[aa]) % 257];
        wx[aa] = w16.x; wy[aa] = -SIGN * w16.y;
    }

    float AX0[2] = {0.f, 0.f}, AY0[2] = {0.f, 0.f}, BX0[2] = {0.f, 0.f}, BY0[2] = {0.f, 0.f};
    float AX1[2] = {0.f, 0.f}, AY1[2] = {0.f, 0.f}, BX1[2] = {0.f, 0.f}, BY1[2] = {0.f, 0.f};

    for (int j = 0; j < 16; ++j) {
        const int tbase = q + 16 * j;
        #pragma unroll
        for (int m = 0; m < 4; ++m) {
            float4 v = col[tbase + 4 * m];
            #pragma unroll
            for (int aa = 0; aa < 2; ++aa) {
                float cxr = cx[aa][m], cyr = cy[aa][m];
                if (m < 2) {
                    AX0[aa] = fmaf(v.x, cxr, AX0[aa]); AX0[aa] = fmaf(-v.y, cyr, AX0[aa]);
                    AY0[aa] = fmaf(v.x, cyr, AY0[aa]); AY0[aa] = fmaf(v.y, cxr, AY0[aa]);
                    BX0[aa] = fmaf(v.z, cxr, BX0[aa]); BX0[aa] = fmaf(-v.w, cyr, BX0[aa]);
                    BY0[aa] = fmaf(v.z, cyr, BY0[aa]); BY0[aa] = fmaf(v.w, cxr, BY0[aa]);
                } else {
                    AX1[aa] = fmaf(v.x, cxr, AX1[aa]); AX1[aa] = fmaf(-v.y, cyr, AX1[aa]);
                    AY1[aa] = fmaf(v.x, cyr, AY1[aa]); AY1[aa] = fmaf(v.y, cxr, AY1[aa]);
                    BX1[aa] = fmaf(v.z, cxr, BX1[aa]); BX1[aa] = fmaf(-v.w, cyr, BX1[aa]);
                    BY1[aa] = fmaf(v.z, cyr, BY1[aa]); BY1[aa] = fmaf(v.w, cxr, BY1[aa]);
                }
                float nx = fmaf(cxr, wx[aa], -cyr * wy[aa]);
                float ny = fmaf(cxr, wy[aa], cyr * wx[aa]);
                cx[aa][m] = nx; cy[aa][m] = ny;
            }
        }
    }

    float ax0[2], ay0[2], ax1[2], ay1[2];
    #pragma unroll
    for (int aa = 0; aa < 2; ++aa) {
        ax0[aa] = AX0[aa] + AX1[aa]; ay0[aa] = AY0[aa] + AY1[aa];
        ax1[aa] = BX0[aa] + BX1[aa]; ay1[aa] = BY0[aa] + BY1[aa];
    }

    if (q == 0) {  // t = 256 term: omega^{256a} = conj(omega^{a})
        float4 v = col[256];
        #pragma unroll
        for (int aa = 0; aa < 2; ++aa) {
            float2 tb = twL[aval[aa]];
            float ex = tb.x, ey = SIGN * tb.y;
            ax0[aa] = fmaf(v.x, ex, ax0[aa]); ax0[aa] = fmaf(-v.y, ey, ax0[aa]);
            ay0[aa] = fmaf(v.x, ey, ay0[aa]); ay0[aa] = fmaf(v.y, ex, ay0[aa]);
            ax1[aa] = fmaf(v.z, ex, ax1[aa]); ax1[aa] = fmaf(-v.w, ey, ax1[aa]);
            ay1[aa] = fmaf(v.z, ey, ay1[aa]); ay1[aa] = fmaf(v.w, ex, ay1[aa]);
        }
    } else {
        #pragma unroll
        for (int aa = 0; aa < 2; ++aa)
            sacc2[q - 1][al][aa] = make_float4(ax0[aa], ay0[aa], ax1[aa], ay1[aa]);
    }
    __syncthreads();

    // mirror validity/targets for MODE<2 (dead otherwise)
    const bool mv0 = (MODE == 0) ? (bc0 <= 127) : (bc0 >= 1 && bc0 <= 128);
    const bool mv1 = ((MODE == 0) ? (bc1 <= 127) : (bc1 >= 1 && bc1 <= 128)) && (bc1 != bc0);
    const int bm0 = (MODE == 0) ? (255 - bc0) : (257 - bc0);
    const int bm1 = (MODE == 0) ? (255 - bc1) : (257 - bc1);
    // MODE 3 psf mirror validity (b=256 column excluded)
    const bool pm = (MODE == 3) && (bc0 <= 127);

    double sum_local = 0.0;
    if (q == 0) {
        #pragma unroll
        for (int aa = 0; aa < 2; ++aa) {
            #pragma unroll
            for (int r = 0; r < 3; ++r) {
                float4 b = sacc2[r][al][aa];
                ax0[aa] += b.x; ay0[aa] += b.y; ax1[aa] += b.z; ay1[aa] += b.w;
            }
            if (MODE < 3) {
                out[(c * NN + aval[aa]) * NN + bc0] = make_float2(ax0[aa], ay0[aa]);
                out[(c * NN + aval[aa]) * NN + bc1] = make_float2(ax1[aa], ay1[aa]);
                if (MODE < 2) {
                    const int a = aval[aa];
                    const int am = (a == 0) ? 0 : (257 - a);
                    if (mv0) {
                        int m = 2 * a + ((MODE == 1) ? 2 * bc0 : 0);
                        m %= 257;
                        float fx = twL[m].x, fy = -SIGN * twL[m].y;
                        out[(c * NN + am) * NN + bm0] =
                            make_float2(ax0[aa] * fx - ay0[aa] * fy, ax0[aa] * fy + ay0[aa] * fx);
                    }
                    if (mv1) {
                        int m = 2 * a + ((MODE == 1) ? 2 * bc1 : 0);
                        m %= 257;
                        float fx = twL[m].x, fy = -SIGN * twL[m].y;
                        out[(c * NN + am) * NN + bm1] =
                            make_float2(ax1[aa] * fx - ay1[aa] * fy, ax1[aa] * fy + ay1[aa] * fx);
                    }
                }
            } else {
                int jj0 = bc0 + 129; if (jj0 >= NN) jj0 -= NN;
                int jj1 = bc1 + 129; if (jj1 >= NN) jj1 -= NN;
                int ii = aval[aa] + 129; if (ii >= NN) ii -= NN;
                float m0 = fmaf(ax0[aa], ax0[aa], ay0[aa] * ay0[aa]) * invn4;
                float m1 = fmaf(ax1[aa], ax1[aa], ay1[aa] * ay1[aa]) * invn4;
                raw[c * PCH + jj0 * PROW + ii] = m0;
                raw[c * PCH + jj1 * PROW + ii] = m1;
                sum_local += (double)m0 + (double)(dupf * m1);
                if (pm) {  // psf point symmetry: psf[j][i] = psf[256-j][256-i]
                    int im = 256 - ii;
                    raw[c * PCH + (256 - jj0) * PROW + im] = m0;
                    raw[c * PCH + (256 - jj1) * PROW + im] = m1;
                    sum_local += (double)m0 + (double)(dupf * m1);
                }
            }
        }
    }

    // ---- a = 256 output (last a-half blocks only): coeff(t) = conj(omega^t) ----
    if (ah == (int)gridDim.x - 1) {
        float c_ = twL[tid].x, s_ = SIGN * twL[tid].y;
        float4 cv = col[tid];
        float tx0 = cv.x * c_ - cv.y * s_;
        float ty0 = cv.x * s_ + cv.y * c_;
        float tx1 = cv.z * c_ - cv.w * s_;
        float ty1 = cv.z * s_ + cv.w * c_;
        if (tid == 0) {
            c_ = twL[256].x; s_ = SIGN * twL[256].y;
            cv = col[256];
            tx0 += cv.x * c_ - cv.y * s_;
            ty0 += cv.x * s_ + cv.y * c_;
            tx1 += cv.z * c_ - cv.w * s_;
            ty1 += cv.z * s_ + cv.w * c_;
        }
        for (int o = 32; o > 0; o >>= 1) {
            tx0 += __shfl_down(tx0, o);
            ty0 += __shfl_down(ty0, o);
            tx1 += __shfl_down(tx1, o);
            ty1 += __shfl_down(ty1, o);
        }
        int wid = tid >> 6;
        if ((tid & 63) == 0) red[wid] = make_float4(tx0, ty0, tx1, ty1);
        __syncthreads();
        if (tid == 0) {
            float Xx0 = red[0].x + red[1].x + red[2].x + red[3].x;
            float Xy0 = red[0].y + red[1].y + red[2].y + red[3].y;
            float Xx1 = red[0].z + red[1].z + red[2].z + red[3].z;
            float Xy1 = red[0].w + red[1].w + red[2].w + red[3].w;
            if (MODE < 3) {
                out[(c * NN + 256) * NN + bc0] = make_float2(Xx0, Xy0);
                out[(c * NN + 256) * NN + bc1] = make_float2(Xx1, Xy1);
                if (MODE < 2) {
                    if (mv0) {
                        int m = 512 + ((MODE == 1) ? 2 * bc0 : 0);
                        m %= 257;
                        float fx = twL[m].x, fy = -SIGN * twL[m].y;
                        out[(c * NN + 1) * NN + bm0] = make_float2(Xx0 * fx - Xy0 * fy, Xx0 * fy + Xy0 * fx);
                    }
                    if (mv1) {
                        int m = 512 + ((MODE == 1) ? 2 * bc1 : 0);
                        m %= 257;
                        float fx = twL[m].x, fy = -SIGN * twL[m].y;
                        out[(c * NN + 1) * NN + bm1] = make_float2(Xx1 * fx - Xy1 * fy, Xx1 * fy + Xy1 * fx);
                    }
                }
            } else {
                int jj0 = bc0 + 129; if (jj0 >= NN) jj0 -= NN;
                int jj1 = bc1 + 129; if (jj1 >= NN) jj1 -= NN;
                float m0 = fmaf(Xx0, Xx0, Xy0 * Xy0) * invn4;
                float m1 = fmaf(Xx1, Xx1, Xy1 * Xy1) * invn4;
                raw[c * PCH + jj0 * PROW + 128] = m0;  // (256+129)%257 == 128
                raw[c * PCH + jj1 * PROW + 128] = m1;
                sum_local += (double)m0 + (double)(dupf * m1);
                if (pm) {
                    raw[c * PCH + (256 - jj0) * PROW + 128] = m0;
                    raw[c * PCH + (256 - jj1) * PROW + 128] = m1;
                    sum_local += (double)m0 + (double)(dupf * m1);
                }
            }
        }
    }

    if (MODE == 3) {
        if (tid < 64) {
            double s = sum_local;
            for (int o = 32; o > 0; o >>= 1) s += __shfl_down(s, o);
            if (tid == 0) atomicAdd(&sums[c], s);
        }
    }
}

// ---------------- conv: 16x per thread (4 acc float4, 5-reg sliding window) ----------------
#define CM16(A, P, Q, iv)                                                                                   \
    A.x = fmaf(iv.x, Q.x, A.x); A.x = fmaf(iv.y, P.w, A.x); A.x = fmaf(iv.z, P.z, A.x); A.x = fmaf(iv.w, P.y, A.x); \
    A.y = fmaf(iv.x, Q.y, A.y); A.y = fmaf(iv.y, Q.x, A.y); A.y = fmaf(iv.z, P.w, A.y); A.y = fmaf(iv.w, P.z, A.y); \
    A.z = fmaf(iv.x, Q.z, A.z); A.z = fmaf(iv.y, Q.y, A.z); A.z = fmaf(iv.z, Q.x, A.z); A.z = fmaf(iv.w, P.w, A.z); \
    A.w = fmaf(iv.x, Q.w, A.w); A.w = fmaf(iv.y, Q.z, A.w); A.w = fmaf(iv.z, Q.y, A.w); A.w = fmaf(iv.w, Q.x, A.w);

__global__ __launch_bounds__(256) void k_conv(const float* __restrict__ img, const float* __restrict__ psf,
                                              float* __restrict__ part) {
    __shared__ float F[8][FSW];       // flipped+swizzled psf rows r0..r0+7
    __shared__ float simg[15][132];   // img rows ulo..ulo+14 (zero outside [0,128))
    __shared__ float sacc[3][4][260];
    const int yt = blockIdx.x;   // 0..15
    const int rz = blockIdx.y;   // 0..16
    const int c = blockIdx.z;
    const int y0 = yt * 8;
    const int r0 = 121 - y0 + 8 * rz;   // psf rows r0..r0+7, within [1,256]
    const int tid = threadIdx.x;
    const int tx = tid & 7;
    const int ty = (tid >> 3) & 7;    // 1 y row each
    const int rh = tid >> 6;          // 2 psf rows each: rr = 2*rh, 2*rh+1
    const int x0 = 16 * tx;
    const int ulo = 8 * rz - 7;       // = y0 + r0 - 128

    for (int g = tid; g < 8 * 65; g += 256) {
        int rr = g / 65, q = g - 65 * rr;
        const float* G = psf + c * PCH + (r0 + rr) * PROW + 4 * q;
        float4 A = *(const float4*)G;
        if (q < 64) {
            F[rr][SW(256 - 4 * q)] = A.x;
            F[rr][SW(255 - 4 * q)] = A.y;
            F[rr][SW(254 - 4 * q)] = A.z;
            F[rr][SW(253 - 4 * q)] = A.w;
        } else {
            F[rr][SW(0)] = A.x;
        }
    }
    for (int g = tid; g < 15 * 32; g += 256) {
        int rw = g >> 5, q = g & 31;
        int u = ulo + rw;
        float4 v = make_float4(0.f, 0.f, 0.f, 0.f);
        if (u >= 0 && u < 128) {
            const float* I = img + (u * 128 + 4 * q) * 3 + c;
            v = make_float4(I[0], I[3], I[6], I[9]);
        }
        *(float4*)&simg[rw][4 * q] = v;
    }
    __syncthreads();

    float4 A0 = make_float4(0.f, 0.f, 0.f, 0.f), A1 = A0, A2 = A0, A3 = A0;

    #pragma unroll
    for (int rr2 = 0; rr2 < 2; ++rr2) {
        const int rr = 2 * rh + rr2;
        const float* Fr = &F[rr][0];
        const float* I = &simg[ty + rr][0];
        float4 W0c = *(const float4*)(Fr + SWG(x0 + 128));
        float4 W1c = *(const float4*)(Fr + SWG(x0 + 132));
        float4 W2c = *(const float4*)(Fr + SWG(x0 + 136));
        float4 W3c = *(const float4*)(Fr + SWG(x0 + 140));
        #pragma unroll 2
        for (int vb = 0; vb < 128; vb += 4) {
            float4 Wm1 = *(const float4*)(Fr + SWG(x0 + 124 - vb));
            float4 iv = *(const float4*)(I + vb);
            CM16(A0, Wm1, W0c, iv)
            CM16(A1, W0c, W1c, iv)
            CM16(A2, W1c, W2c, iv)
            CM16(A3, W2c, W3c, iv)
            W3c = W2c; W2c = W1c; W1c = W0c; W0c = Wm1;
        }
    }

    if (rh != 0) {
        int s = tid & 63;
        *(float4*)&sacc[rh - 1][0][4 * s] = A0;
        *(float4*)&sacc[rh - 1][1][4 * s] = A1;
        *(float4*)&sacc[rh - 1][2][4 * s] = A2;
        *(float4*)&sacc[rh - 1][3][4 * s] = A3;
    }
    __syncthreads();
    if (rh == 0) {
        int s = tid;  // 0..63 encodes (ty, tx)
        #pragma unroll
        for (int r = 0; r < 3; ++r) {
            float4 b0 = *(const float4*)&sacc[r][0][4 * s];
            float4 b1 = *(const float4*)&sacc[r][1][4 * s];
            float4 b2 = *(const float4*)&sacc[r][2][4 * s];
            float4 b3 = *(const float4*)&sacc[r][3][4 * s];
            A0.x += b0.x; A0.y += b0.y; A0.z += b0.z; A0.w += b0.w;
            A1.x += b1.x; A1.y += b1.y; A1.z += b1.z; A1.w += b1.w;
            A2.x += b2.x; A2.y += b2.y; A2.z += b2.z; A2.w += b2.w;
            A3.x += b3.x; A3.y += b3.y; A3.z += b3.z; A3.w += b3.w;
        }
        const int y = y0 + ty;
        float* dst = part + ((rz * 3 + c) * 128 + y) * 128 + x0;
        *(float4*)dst = A0;
        *(float4*)(dst + 4) = A1;
        *(float4*)(dst + 8) = A2;
        *(float4*)(dst + 12) = A3;
    }
}

// ---------------- final: combine conv partials + psf normalize ----------------
__global__ __launch_bounds__(256) void k_final(const float* __restrict__ part, const float* __restrict__ raw,
                                               const double* __restrict__ sums, float* __restrict__ out) {
    int gid = blockIdx.x * 256 + threadIdx.x;
    if (gid < 49152) {
        int c = gid >> 14;
        int r = gid & 16383;
        float s = 0.f;
        #pragma unroll
        for (int rz = 0; rz < NRZ; ++rz) s += part[((rz * 3 + c) * 128 + (r >> 7)) * 128 + (r & 127)];
        float inv = (float)(1.0 / (sums[c] + 1e-7));
        out[r * 3 + c] = s * inv;
    } else {
        int o = gid - 49152;
        if (o < 3 * NN2) {
            int idx = o / 3, c = o - 3 * idx;
            int j = idx / NN, i = idx - NN * j;
            float inv = (float)(1.0 / (sums[c] + 1e-7));
            out[49152 + o] = raw[c * PCH + j * PROW + i] * inv;
        }
    }
}

extern "C" void kernel_launch(void* const* d_in, const int* in_sizes, int n_in,
                              void* d_out, int out_size, void* d_ws, size_t ws_size,
                              hipStream_t stream) {
    const float* img = (const float*)d_in[0];    // (128,128,3) f32
    const float* depth = (const float*)d_in[1];  // (128,128) f32
    float* out = (float*)d_out;                  // 49152 (image) + 198147 (psf)

    char* ws = (char*)d_ws;
    double* zsums = (double*)ws;                       // 3 psf channel sums (zeroed by pass 3)
    float2* bufA = (float2*)(ws + 64);                 // 3*NN2 complex (transposed layout)
    float2* bufB = bufA + 3 * NN2;                     // 3*NN2 complex (transposed layout)
    float* raw = (float*)(bufB + 3 * NN2);             // 3*PCH floats (padded planar |u|^2/N^4)
    float* part = raw + 3 * PCH;                       // NRZ*3*16384 floats

    k_dft<-1, 0><<<dim3(2, 65, 3), 256, 0, stream>>>(nullptr, bufA, depth, nullptr, nullptr);
    k_dft<-1, 1><<<dim3(2, 65, 3), 256, 0, stream>>>(bufA, bufB, nullptr, nullptr, nullptr);
    k_dft< 1, 2><<<dim3(2, 129, 3), 256, 0, stream>>>(bufB, bufA, nullptr, nullptr, zsums);
    k_dft< 1, 3><<<dim3(2, 65, 3), 256, 0, stream>>>(bufA, nullptr, nullptr, raw, zsums);
    k_conv<<<dim3(16, NRZ, 3), 256, 0, stream>>>(img, raw, part);
    k_final<<<(49152 + 3 * NN2 + 255) / 256, 256, 0, stream>>>(part, raw, zsums, out);
}

// Round 21
// 77.812 us; speedup vs baseline: 1.0687x; 1.0687x over previous
//
#include <hip/hip_runtime.h>
#include <math.h>

#define NN 257
#define NN2 66049        // 257*257
#define PROW 260         // padded psf row stride (floats)
#define PCH (PROW * NN)
#define NRZ 17           // psf-row chunks of 8 (17*8=136 >= 135 rows per y-tile of 8)
#define FSW 288

#define SWG(f) (((((f) >> 2) ^ (((f) >> 5) & 7)) << 2))
#define SW(f) (SWG(f) | ((f) & 3))

static const double D_PI = 3.14159265358979323846;

__device__ __forceinline__ double lam_of(int c) {
    return c == 0 ? 610e-9 : (c == 1 ? 530e-9 : 470e-9);
}

__device__ __forceinline__ float2 phase_of(double rev) {
    rev -= floor(rev);
    float ang = (float)(2.0 * D_PI * rev);
    float sv, cv;
    __sincosf(ang, &sv, &cv);
    return make_float2(cv, sv);
}

// ---------------- DFT pass: 2 b-columns/block, 2 a-values/thread (R17 known-good) ----------------
// Math: out(b, a) = sum_t colval(t,b) * exp(SIGN*2*pi*i*a*t/257)
// STORAGE TRANSPOSED: element (b, a) at out[(c*NN + a)*NN + b] -> coalesced staging reads.
// MODE 0: aperture field generated (z1 = in-block depth mean); b in {0..127, 256};
//         mirror out(255-b, (257-a)%257) = w^{2a} * out(b, a)
// MODE 1: b in {0..128}; mirror out(257-b, (257-a)%257) = w^{2(a+b)} * out(b, a)
// MODE 2: H-mult, full b, a in {0..127, 256} only (grid.x = 1); zeroes sums[c]
// MODE 3: b in {0..127, 256}; |.|^2 into raw, mirrored via psf point symmetry
template <int SIGN, int MODE>
__global__ __launch_bounds__(256) void k_dft(const float2* __restrict__ in, float2* __restrict__ out,
                                             const float* __restrict__ depth,
                                             float* __restrict__ raw, double* __restrict__ sums) {
    __shared__ float4 col[NN];       // {re0, im0, re1, im1}
    __shared__ float2 twL[NN];
    __shared__ float4 sacc2[3][64][2];
    __shared__ float4 red[4];
    const int ah = blockIdx.x;       // a-half
    const int by = blockIdx.y;       // b-pair
    const int c = blockIdx.z;
    int bc0, bc1;
    if (MODE == 0 || MODE == 3) {
        bc0 = (by < 64) ? 2 * by : 256;
        bc1 = (by < 64) ? bc0 + 1 : 256;
    } else if (MODE == 1) {
        bc0 = (by < 64) ? 2 * by : 128;
        bc1 = (by < 64) ? bc0 + 1 : 128;
    } else {
        bc0 = 2 * by;
        bc1 = (bc0 < 256) ? bc0 + 1 : 256;
    }
    const float dupf = (bc1 == bc0) ? 0.f : 1.f;
    const int tid = threadIdx.x;

    if (MODE == 2) {  // zero channel sums ahead of pass 4 (stream-ordered)
        if (ah == 0 && by == 0 && tid == 0) sums[c] = 0.0;
    }

    // ---- twiddle table ----
    for (int t = tid; t < NN; t += 256) {
        double th = 2.0 * D_PI * (double)t / 257.0;
        double sv, cv; sincos(th, &sv, &cv);
        twL[t] = make_float2((float)cv, (float)(-sv));   // exp(-2*pi*i*t/257)
    }

    // ---- MODE 0: block-local depth mean (identical reduction order -> identical z1) ----
    double z1 = 0.0;
    if (MODE == 0) {
        double* sred = (double*)sacc2;
        double acc = 0.0;
        for (int i = tid; i < 16384; i += 256) acc += (double)depth[i];
        sred[tid] = acc;
        __syncthreads();
        for (int o = 128; o > 0; o >>= 1) {
            if (tid < o) sred[tid] += sred[tid + o];
            __syncthreads();
        }
        z1 = sred[0] / 16384.0;
        __syncthreads();
    }

    for (int t = tid; t < NN; t += 256) {
        float2 v0, v1;
        if (MODE == 0) {
            int js = t + 129; if (js >= NN) js -= NN;
            const double step = 0.01 / 256.0;
            double yy = -0.005 + js * step;
            double lam = lam_of(c);
            const double ap = 0.5 * (0.01 / 257.0) * 128.0 + 1e-7;
            {
                int is = bc0 + 129; if (is >= NN) is -= NN;
                double x = -0.005 + is * step;
                double r2 = x * x + yy * yy;
                v0 = make_float2(0.f, 0.f);
                if (sqrt(r2) <= ap) v0 = phase_of(sqrt(r2 + z1 * z1) / lam);
            }
            {
                int is = bc1 + 129; if (is >= NN) is -= NN;
                double x = -0.005 + is * step;
                double r2 = x * x + yy * yy;
                v1 = make_float2(0.f, 0.f);
                if (sqrt(r2) <= ap) v1 = phase_of(sqrt(r2 + z1 * z1) / lam);
            }
        } else {
            v0 = in[(c * NN + bc0) * NN + t];   // coalesced (transposed layout)
            v1 = in[(c * NN + bc1) * NN + t];
            if (MODE == 2) {
                int ps = t + 129; if (ps >= NN) ps -= NN;
                const double fstep = 25700.0 / 256.0;
                double fy = -12850.0 + ps * fstep;
                double lam = lam_of(c);
                double ilam2 = 1.0 / (lam * lam);
                double kzr = 0.05 / lam;
                {
                    int qs = bc0 + 129; if (qs >= NN) qs -= NN;
                    double fx = -12850.0 + qs * fstep;
                    double lfx = lam * fx, lfy = lam * fy;
                    double a2 = 1.0 - lfx * lfx - lfy * lfy;
                    float2 hh = make_float2(0.f, 0.f);
                    if (fx * fx + fy * fy < ilam2) hh = phase_of(kzr * sqrt(a2 > 0.0 ? a2 : 0.0));
                    v0 = make_float2(v0.x * hh.x - v0.y * hh.y, v0.x * hh.y + v0.y * hh.x);
                }
                {
                    int qs = bc1 + 129; if (qs >= NN) qs -= NN;
                    double fx = -12850.0 + qs * fstep;
                    double lfx = lam * fx, lfy = lam * fy;
                    double a2 = 1.0 - lfx * lfx - lfy * lfy;
                    float2 hh = make_float2(0.f, 0.f);
                    if (fx * fx + fy * fy < ilam2) hh = phase_of(kzr * sqrt(a2 > 0.0 ? a2 : 0.0));
                    v1 = make_float2(v1.x * hh.x - v1.y * hh.y, v1.x * hh.y + v1.y * hh.x);
                }
            }
        }
        col[t] = make_float4(v0.x, v0.y, v1.x, v1.y);
    }
    __syncthreads();

    const float invn4 = (float)(1.0 / ((double)NN2 * (double)NN2));
    const int q = tid >> 6;          // t-quarter (t ≡ q mod 4)
    const int al = tid & 63;
    int aval[2];
    aval[0] = ah * 128 + al;
    aval[1] = aval[0] + 64;

    // per-a: 4 twiddle chains (t = q+4m+16j), step omega^{16a}
    float cx[2][4], cy[2][4], wx[2], wy[2];
    #pragma unroll
    for (int aa = 0; aa < 2; ++aa) {
        #pragma unroll
        for (int m = 0; m < 4; ++m) {
            int sm = (aval[aa] * (q + 4 * m)) % 257;
            float2 tt = twL[sm];
            cx[aa][m] = tt.x; cy[aa][m] = -SIGN * tt.y;
        }
        float2 w16 = twL[(16 * aval[aa]) % 257];
        wx[aa] = w16.x; wy[aa] = -SIGN * w16.y;
    }

    float AX0[2] = {0.f, 0.f}, AY0[2] = {0.f, 0.f}, BX0[2] = {0.f, 0.f}, BY0[2] = {0.f, 0.f};
    float AX1[2] = {0.f, 0.f}, AY1[2] = {0.f, 0.f}, BX1[2] = {0.f, 0.f}, BY1[2] = {0.f, 0.f};

    for (int j = 0; j < 16; ++j) {
        const int tbase = q + 16 * j;
        #pragma unroll
        for (int m = 0; m < 4; ++m) {
            float4 v = col[tbase + 4 * m];
            #pragma unroll
            for (int aa = 0; aa < 2; ++aa) {
                float cxr = cx[aa][m], cyr = cy[aa][m];
                if (m < 2) {
                    AX0[aa] = fmaf(v.x, cxr, AX0[aa]); AX0[aa] = fmaf(-v.y, cyr, AX0[aa]);
                    AY0[aa] = fmaf(v.x, cyr, AY0[aa]); AY0[aa] = fmaf(v.y, cxr, AY0[aa]);
                    BX0[aa] = fmaf(v.z, cxr, BX0[aa]); BX0[aa] = fmaf(-v.w, cyr, BX0[aa]);
                    BY0[aa] = fmaf(v.z, cyr, BY0[aa]); BY0[aa] = fmaf(v.w, cxr, BY0[aa]);
                } else {
                    AX1[aa] = fmaf(v.x, cxr, AX1[aa]); AX1[aa] = fmaf(-v.y, cyr, AX1[aa]);
                    AY1[aa] = fmaf(v.x, cyr, AY1[aa]); AY1[aa] = fmaf(v.y, cxr, AY1[aa]);
                    BX1[aa] = fmaf(v.z, cxr, BX1[aa]); BX1[aa] = fmaf(-v.w, cyr, BX1[aa]);
                    BY1[aa] = fmaf(v.z, cyr, BY1[aa]); BY1[aa] = fmaf(v.w, cxr, BY1[aa]);
                }
                float nx = fmaf(cxr, wx[aa], -cyr * wy[aa]);
                float ny = fmaf(cxr, wy[aa], cyr * wx[aa]);
                cx[aa][m] = nx; cy[aa][m] = ny;
            }
        }
    }

    float ax0[2], ay0[2], ax1[2], ay1[2];
    #pragma unroll
    for (int aa = 0; aa < 2; ++aa) {
        ax0[aa] = AX0[aa] + AX1[aa]; ay0[aa] = AY0[aa] + AY1[aa];
        ax1[aa] = BX0[aa] + BX1[aa]; ay1[aa] = BY0[aa] + BY1[aa];
    }

    if (q == 0) {  // t = 256 term: omega^{256a} = conj(omega^{a})
        float4 v = col[256];
        #pragma unroll
        for (int aa = 0; aa < 2; ++aa) {
            float2 tb = twL[aval[aa]];
            float ex = tb.x, ey = SIGN * tb.y;
            ax0[aa] = fmaf(v.x, ex, ax0[aa]); ax0[aa] = fmaf(-v.y, ey, ax0[aa]);
            ay0[aa] = fmaf(v.x, ey, ay0[aa]); ay0[aa] = fmaf(v.y, ex, ay0[aa]);
            ax1[aa] = fmaf(v.z, ex, ax1[aa]); ax1[aa] = fmaf(-v.w, ey, ax1[aa]);
            ay1[aa] = fmaf(v.z, ey, ay1[aa]); ay1[aa] = fmaf(v.w, ex, ay1[aa]);
        }
    } else {
        #pragma unroll
        for (int aa = 0; aa < 2; ++aa)
            sacc2[q - 1][al][aa] = make_float4(ax0[aa], ay0[aa], ax1[aa], ay1[aa]);
    }
    __syncthreads();

    // mirror validity/targets for MODE<2 (dead otherwise)
    const bool mv0 = (MODE == 0) ? (bc0 <= 127) : (bc0 >= 1 && bc0 <= 128);
    const bool mv1 = ((MODE == 0) ? (bc1 <= 127) : (bc1 >= 1 && bc1 <= 128)) && (bc1 != bc0);
    const int bm0 = (MODE == 0) ? (255 - bc0) : (257 - bc0);
    const int bm1 = (MODE == 0) ? (255 - bc1) : (257 - bc1);
    // MODE 3 psf mirror validity (b=256 column excluded)
    const bool pm = (MODE == 3) && (bc0 <= 127);

    double sum_local = 0.0;
    if (q == 0) {
        #pragma unroll
        for (int aa = 0; aa < 2; ++aa) {
            #pragma unroll
            for (int r = 0; r < 3; ++r) {
                float4 b = sacc2[r][al][aa];
                ax0[aa] += b.x; ay0[aa] += b.y; ax1[aa] += b.z; ay1[aa] += b.w;
            }
            if (MODE < 3) {
                out[(c * NN + aval[aa]) * NN + bc0] = make_float2(ax0[aa], ay0[aa]);
                out[(c * NN + aval[aa]) * NN + bc1] = make_float2(ax1[aa], ay1[aa]);
                if (MODE < 2) {
                    const int a = aval[aa];
                    const int am = (a == 0) ? 0 : (257 - a);
                    if (mv0) {
                        int m = 2 * a + ((MODE == 1) ? 2 * bc0 : 0);
                        m %= 257;
                        float fx = twL[m].x, fy = -SIGN * twL[m].y;
                        out[(c * NN + am) * NN + bm0] =
                            make_float2(ax0[aa] * fx - ay0[aa] * fy, ax0[aa] * fy + ay0[aa] * fx);
                    }
                    if (mv1) {
                        int m = 2 * a + ((MODE == 1) ? 2 * bc1 : 0);
                        m %= 257;
                        float fx = twL[m].x, fy = -SIGN * twL[m].y;
                        out[(c * NN + am) * NN + bm1] =
                            make_float2(ax1[aa] * fx - ay1[aa] * fy, ax1[aa] * fy + ay1[aa] * fx);
                    }
                }
            } else {
                int jj0 = bc0 + 129; if (jj0 >= NN) jj0 -= NN;
                int jj1 = bc1 + 129; if (jj1 >= NN) jj1 -= NN;
                int ii = aval[aa] + 129; if (ii >= NN) ii -= NN;
                float m0 = fmaf(ax0[aa], ax0[aa], ay0[aa] * ay0[aa]) * invn4;
                float m1 = fmaf(ax1[aa], ax1[aa], ay1[aa] * ay1[aa]) * invn4;
                raw[c * PCH + jj0 * PROW + ii] = m0;
                raw[c * PCH + jj1 * PROW + ii] = m1;
                sum_local += (double)m0 + (double)(dupf * m1);
                if (pm) {  // psf point symmetry: psf[j][i] = psf[256-j][256-i]
                    int im = 256 - ii;
                    raw[c * PCH + (256 - jj0) * PROW + im] = m0;
                    raw[c * PCH + (256 - jj1) * PROW + im] = m1;
                    sum_local += (double)m0 + (double)(dupf * m1);
                }
            }
        }
    }

    // ---- a = 256 output (last a-half blocks only): coeff(t) = conj(omega^t) ----
    if (ah == (int)gridDim.x - 1) {
        float c_ = twL[tid].x, s_ = SIGN * twL[tid].y;
        float4 cv = col[tid];
        float tx0 = cv.x * c_ - cv.y * s_;
        float ty0 = cv.x * s_ + cv.y * c_;
        float tx1 = cv.z * c_ - cv.w * s_;
        float ty1 = cv.z * s_ + cv.w * c_;
        if (tid == 0) {
            c_ = twL[256].x; s_ = SIGN * twL[256].y;
            cv = col[256];
            tx0 += cv.x * c_ - cv.y * s_;
            ty0 += cv.x * s_ + cv.y * c_;
            tx1 += cv.z * c_ - cv.w * s_;
            ty1 += cv.z * s_ + cv.w * c_;
        }
        for (int o = 32; o > 0; o >>= 1) {
            tx0 += __shfl_down(tx0, o);
            ty0 += __shfl_down(ty0, o);
            tx1 += __shfl_down(tx1, o);
            ty1 += __shfl_down(ty1, o);
        }
        int wid = tid >> 6;
        if ((tid & 63) == 0) red[wid] = make_float4(tx0, ty0, tx1, ty1);
        __syncthreads();
        if (tid == 0) {
            float Xx0 = red[0].x + red[1].x + red[2].x + red[3].x;
            float Xy0 = red[0].y + red[1].y + red[2].y + red[3].y;
            float Xx1 = red[0].z + red[1].z + red[2].z + red[3].z;
            float Xy1 = red[0].w + red[1].w + red[2].w + red[3].w;
            if (MODE < 3) {
                out[(c * NN + 256) * NN + bc0] = make_float2(Xx0, Xy0);
                out[(c * NN + 256) * NN + bc1] = make_float2(Xx1, Xy1);
                if (MODE < 2) {
                    if (mv0) {
                        int m = 512 + ((MODE == 1) ? 2 * bc0 : 0);
                        m %= 257;
                        float fx = twL[m].x, fy = -SIGN * twL[m].y;
                        out[(c * NN + 1) * NN + bm0] = make_float2(Xx0 * fx - Xy0 * fy, Xx0 * fy + Xy0 * fx);
                    }
                    if (mv1) {
                        int m = 512 + ((MODE == 1) ? 2 * bc1 : 0);
                        m %= 257;
                        float fx = twL[m].x, fy = -SIGN * twL[m].y;
                        out[(c * NN + 1) * NN + bm1] = make_float2(Xx1 * fx - Xy1 * fy, Xx1 * fy + Xy1 * fx);
                    }
                }
            } else {
                int jj0 = bc0 + 129; if (jj0 >= NN) jj0 -= NN;
                int jj1 = bc1 + 129; if (jj1 >= NN) jj1 -= NN;
                float m0 = fmaf(Xx0, Xx0, Xy0 * Xy0) * invn4;
                float m1 = fmaf(Xx1, Xx1, Xy1 * Xy1) * invn4;
                raw[c * PCH + jj0 * PROW + 128] = m0;  // (256+129)%257 == 128
                raw[c * PCH + jj1 * PROW + 128] = m1;
                sum_local += (double)m0 + (double)(dupf * m1);
                if (pm) {
                    raw[c * PCH + (256 - jj0) * PROW + 128] = m0;
                    raw[c * PCH + (256 - jj1) * PROW + 128] = m1;
                    sum_local += (double)m0 + (double)(dupf * m1);
                }
            }
        }
    }

    if (MODE == 3) {
        if (tid < 64) {
            double s = sum_local;
            for (int o = 32; o > 0; o >>= 1) s += __shfl_down(s, o);
            if (tid == 0) atomicAdd(&sums[c], s);
        }
    }
}

// ---------------- conv: 16x per thread (4 acc float4, 5-reg sliding window) ----------------
#define CM16(A, P, Q, iv)                                                                                   \
    A.x = fmaf(iv.x, Q.x, A.x); A.x = fmaf(iv.y, P.w, A.x); A.x = fmaf(iv.z, P.z, A.x); A.x = fmaf(iv.w, P.y, A.x); \
    A.y = fmaf(iv.x, Q.y, A.y); A.y = fmaf(iv.y, Q.x, A.y); A.y = fmaf(iv.z, P.w, A.y); A.y = fmaf(iv.w, P.z, A.y); \
    A.z = fmaf(iv.x, Q.z, A.z); A.z = fmaf(iv.y, Q.y, A.z); A.z = fmaf(iv.z, Q.x, A.z); A.z = fmaf(iv.w, P.w, A.z); \
    A.w = fmaf(iv.x, Q.w, A.w); A.w = fmaf(iv.y, Q.z, A.w); A.w = fmaf(iv.z, Q.y, A.w); A.w = fmaf(iv.w, Q.x, A.w);

__global__ __launch_bounds__(256) void k_conv(const float* __restrict__ img, const float* __restrict__ psf,
                                              float* __restrict__ part) {
    __shared__ float F[8][FSW];       // flipped+swizzled psf rows r0..r0+7
    __shared__ float simg[15][132];   // img rows ulo..ulo+14 (zero outside [0,128))
    __shared__ float sacc[3][4][260];
    const int yt = blockIdx.x;   // 0..15
    const int rz = blockIdx.y;   // 0..16
    const int c = blockIdx.z;
    const int y0 = yt * 8;
    const int r0 = 121 - y0 + 8 * rz;   // psf rows r0..r0+7, within [1,256]
    const int tid = threadIdx.x;
    const int tx = tid & 7;
    const int ty = (tid >> 3) & 7;    // 1 y row each
    const int rh = tid >> 6;          // 2 psf rows each: rr = 2*rh, 2*rh+1
    const int x0 = 16 * tx;
    const int ulo = 8 * rz - 7;       // = y0 + r0 - 128

    for (int g = tid; g < 8 * 65; g += 256) {
        int rr = g / 65, q = g - 65 * rr;
        const float* G = psf + c * PCH + (r0 + rr) * PROW + 4 * q;
        float4 A = *(const float4*)G;
        if (q < 64) {
            F[rr][SW(256 - 4 * q)] = A.x;
            F[rr][SW(255 - 4 * q)] = A.y;
            F[rr][SW(254 - 4 * q)] = A.z;
            F[rr][SW(253 - 4 * q)] = A.w;
        } else {
            F[rr][SW(0)] = A.x;
        }
    }
    for (int g = tid; g < 15 * 32; g += 256) {
        int rw = g >> 5, q = g & 31;
        int u = ulo + rw;
        float4 v = make_float4(0.f, 0.f, 0.f, 0.f);
        if (u >= 0 && u < 128) {
            const float* I = img + (u * 128 + 4 * q) * 3 + c;
            v = make_float4(I[0], I[3], I[6], I[9]);
        }
        *(float4*)&simg[rw][4 * q] = v;
    }
    __syncthreads();

    float4 A0 = make_float4(0.f, 0.f, 0.f, 0.f), A1 = A0, A2 = A0, A3 = A0;

    #pragma unroll
    for (int rr2 = 0; rr2 < 2; ++rr2) {
        const int rr = 2 * rh + rr2;
        const float* Fr = &F[rr][0];
        const float* I = &simg[ty + rr][0];
        float4 W0c = *(const float4*)(Fr + SWG(x0 + 128));
        float4 W1c = *(const float4*)(Fr + SWG(x0 + 132));
        float4 W2c = *(const float4*)(Fr + SWG(x0 + 136));
        float4 W3c = *(const float4*)(Fr + SWG(x0 + 140));
        #pragma unroll 2
        for (int vb = 0; vb < 128; vb += 4) {
            float4 Wm1 = *(const float4*)(Fr + SWG(x0 + 124 - vb));
            float4 iv = *(const float4*)(I + vb);
            CM16(A0, Wm1, W0c, iv)
            CM16(A1, W0c, W1c, iv)
            CM16(A2, W1c, W2c, iv)
            CM16(A3, W2c, W3c, iv)
            W3c = W2c; W2c = W1c; W1c = W0c; W0c = Wm1;
        }
    }

    if (rh != 0) {
        int s = tid & 63;
        *(float4*)&sacc[rh - 1][0][4 * s] = A0;
        *(float4*)&sacc[rh - 1][1][4 * s] = A1;
        *(float4*)&sacc[rh - 1][2][4 * s] = A2;
        *(float4*)&sacc[rh - 1][3][4 * s] = A3;
    }
    __syncthreads();
    if (rh == 0) {
        int s = tid;  // 0..63 encodes (ty, tx)
        #pragma unroll
        for (int r = 0; r < 3; ++r) {
            float4 b0 = *(const float4*)&sacc[r][0][4 * s];
            float4 b1 = *(const float4*)&sacc[r][1][4 * s];
            float4 b2 = *(const float4*)&sacc[r][2][4 * s];
            float4 b3 = *(const float4*)&sacc[r][3][4 * s];
            A0.x += b0.x; A0.y += b0.y; A0.z += b0.z; A0.w += b0.w;
            A1.x += b1.x; A1.y += b1.y; A1.z += b1.z; A1.w += b1.w;
            A2.x += b2.x; A2.y += b2.y; A2.z += b2.z; A2.w += b2.w;
            A3.x += b3.x; A3.y += b3.y; A3.z += b3.z; A3.w += b3.w;
        }
        const int y = y0 + ty;
        float* dst = part + ((rz * 3 + c) * 128 + y) * 128 + x0;
        *(float4*)dst = A0;
        *(float4*)(dst + 4) = A1;
        *(float4*)(dst + 8) = A2;
        *(float4*)(dst + 12) = A3;
    }
}

// ---------------- final: combine conv partials + psf normalize ----------------
__global__ __launch_bounds__(256) void k_final(const float* __restrict__ part, const float* __restrict__ raw,
                                               const double* __restrict__ sums, float* __restrict__ out) {
    int gid = blockIdx.x * 256 + threadIdx.x;
    if (gid < 49152) {
        int c = gid >> 14;
        int r = gid & 16383;
        float s = 0.f;
        #pragma unroll
        for (int rz = 0; rz < NRZ; ++rz) s += part[((rz * 3 + c) * 128 + (r >> 7)) * 128 + (r & 127)];
        float inv = (float)(1.0 / (sums[c] + 1e-7));
        out[r * 3 + c] = s * inv;
    } else {
        int o = gid - 49152;
        if (o < 3 * NN2) {
            int idx = o / 3, c = o - 3 * idx;
            int j = idx / NN, i = idx - NN * j;
            float inv = (float)(1.0 / (sums[c] + 1e-7));
            out[49152 + o] = raw[c * PCH + j * PROW + i] * inv;
        }
    }
}

extern "C" void kernel_launch(void* const* d_in, const int* in_sizes, int n_in,
                              void* d_out, int out_size, void* d_ws, size_t ws_size,
                              hipStream_t stream) {
    const float* img = (const float*)d_in[0];    // (128,128,3) f32
    const float* depth = (const float*)d_in[1];  // (128,128) f32
    float* out = (float*)d_out;                  // 49152 (image) + 198147 (psf)

    char* ws = (char*)d_ws;
    double* zsums = (double*)ws;                       // 3 psf channel sums (zeroed by pass 3)
    float2* bufA = (float2*)(ws + 64);                 // 3*NN2 complex (transposed layout)
    float2* bufB = bufA + 3 * NN2;                     // 3*NN2 complex (transposed layout)
    float* raw = (float*)(bufB + 3 * NN2);             // 3*PCH floats (padded planar |u|^2/N^4)
    float* part = raw + 3 * PCH;                       // NRZ*3*16384 floats

    k_dft<-1, 0><<<dim3(2, 65, 3), 256, 0, stream>>>(nullptr, bufA, depth, nullptr, nullptr);
    k_dft<-1, 1><<<dim3(2, 65, 3), 256, 0, stream>>>(bufA, bufB, nullptr, nullptr, nullptr);
    k_dft< 1, 2><<<dim3(1, 129, 3), 256, 0, stream>>>(bufB, bufA, nullptr, nullptr, zsums);
    k_dft< 1, 3><<<dim3(2, 65, 3), 256, 0, stream>>>(bufA, nullptr, nullptr, raw, zsums);
    k_conv<<<dim3(16, NRZ, 3), 256, 0, stream>>>(img, raw, part);
    k_final<<<(49152 + 3 * NN2 + 255) / 256, 256, 0, stream>>>(part, raw, zsums, out);
}